// Round 9
// baseline (1342.193 us; speedup 1.0000x reference)
//
#include <hip/hip_runtime.h>
#include <math.h>

// Problem dims (fixed): B=2, S=2048 -> TOK=4096 tokens; H=4096; I=11008
#define TOK 4096
#define HD  4096
#define ID  11008

typedef int i32x4 __attribute__((ext_vector_type(4)));
typedef float f32x4v __attribute__((ext_vector_type(4)));
typedef char i8x4v __attribute__((ext_vector_type(4)));

#define GLDS16(g, l) __builtin_amdgcn_global_load_lds( \
    (const __attribute__((address_space(1))) void*)(g), \
    (__attribute__((address_space(3))) void*)(l), 16, 0, 0)

// ---------------------------------------------------------------- convert ---
__global__ void conv_all(const float* __restrict__ x,  char* __restrict__ xq,
                         const float* __restrict__ wg, char* __restrict__ wgq,
                         const float* __restrict__ wu, char* __restrict__ wuq,
                         const float* __restrict__ wd, char* __restrict__ wdq)
{
  const long NX = (long)TOK * HD / 4, NW = (long)ID * HD / 4;
  const long total = NX + 3 * NW;
  const long stride = (long)gridDim.x * blockDim.x;
  for (long i = (long)blockIdx.x * blockDim.x + threadIdx.x; i < total;
       i += stride) {
    const f32x4v* src; i8x4v* dst; long j;
    if (i < NX)               { src = (const f32x4v*)x;  dst = (i8x4v*)xq;  j = i; }
    else if (i < NX + NW)     { src = (const f32x4v*)wg; dst = (i8x4v*)wgq; j = i - NX; }
    else if (i < NX + 2 * NW) { src = (const f32x4v*)wu; dst = (i8x4v*)wuq; j = i - NX - NW; }
    else                      { src = (const f32x4v*)wd; dst = (i8x4v*)wdq; j = i - NX - 2 * NW; }
    f32x4v v = __builtin_nontemporal_load(&src[j]);
    i8x4v o;
    o.x = (char)(int)rintf(v.x);
    o.y = (char)(int)rintf(v.y);
    o.z = (char)(int)rintf(v.z);
    o.w = (char)(int)rintf(v.w);
    dst[j] = o;
  }
}

// ----------------------------------------------------------------- GEMM -----
// out[m,n] = sum_k A[m,k]*B[n,k]  (both K-major int8), i32 accumulate (exact).
// BK=128, 128x128 tile, 32 MFMA per barrier, XOR-swizzled LDS (0 conflicts),
// coalesced glds width=16, XCD-aware block swizzle (R6).
//
// R9: K-PHASE OFFSET. The 4 same-XCD blocks sharing a B-tile run in lockstep,
// so their per-stage B loads were CONCURRENT misses (MSHR-merged -> minimal
// FETCH, but all 4 blocks wait the full ~900cyc fill every stage). Integer
// accumulation is order-independent, so each block starts its K-loop at
// phase*nst/4 stages (phase = (L>>3)&3) and wraps: the 4 blocks now read
// different K-slices at any instant, and 3 of 4 B-slice reads become
// temporal L2 hits (~250cyc) instead of merged 900cyc stalls.
//
// MODE 0: gate -> ga = silu(acc*gs);  MODE 1: up -> inter;  MODE 2: down
template<int MODE>
__global__ __launch_bounds__(256, 3)
void gemm_i8(const char* __restrict__ A,
             const char* __restrict__ Bm,
             int M, int N, int K,
             float* __restrict__ Cout,
             const float* __restrict__ ga_in,
             const float* __restrict__ sc0,
             const float* __restrict__ sc1,
             double* __restrict__ sums,
             long long NN)
{
  __shared__ char As[16384];
  __shared__ char Bs[16384];
  __shared__ double red[4];

  const int tid  = threadIdx.x;
  const int w    = tid >> 6;        // wave 0..3
  const int lane = tid & 63;
  const int wr   = lane & 15;
  const int qd   = lane >> 4;
  const int wm   = (w >> 1) << 6;
  const int wn   = (w & 1) << 6;

  // XCD-aware swizzle (bijection over all (m_tile, n_tile))
  const int L   = blockIdx.y * gridDim.x + blockIdx.x;
  const int xcd = L & 7;
  const int r   = L >> 3;
  const int m0  = (xcd + ((r & 3) << 3)) << 7;
  const int n0  = (r >> 2) << 7;

  i32x4 acc[4][4] = {};

  // staging addresses
  const int rowL = tid >> 3;                    // 0..31
  const int chk  = (tid & 7) ^ (rowL & 7);
  const char* gA = A  + (size_t)(m0 + rowL) * K + (chk << 4);
  const char* gB = Bm + (size_t)(n0 + rowL) * K + (chk << 4);
  const size_t rk32 = (size_t)32 * K;
  char* lA = As + (w << 10);
  char* lB = Bs + (w << 10);

  // fragment LDS byte offsets (loop-invariant)
  const int s7    = wr & 7;
  const int abase = ((wm + wr) << 7) + ((qd ^ s7) << 4);
  const int bbase = ((wn + wr) << 7) + ((qd ^ s7) << 4);

  // K-phase offset: start at (phase * nst / 4) stages, wrap at K
  const int nst   = K >> 7;                     // stages of 128
  const int phase = (r & 3);
  int kk = ((phase * nst) >> 2) << 7;           // multiple of 128, < K

  for (int s = 0; s < nst; s++) {
    const int k0 = kk;
    kk += 128; if (kk >= K) kk = 0;

    GLDS16(gA + k0,            lA);
    GLDS16(gA + k0 +     rk32, lA + 4096);
    GLDS16(gA + k0 + 2 * rk32, lA + 8192);
    GLDS16(gA + k0 + 3 * rk32, lA + 12288);
    GLDS16(gB + k0,            lB);
    GLDS16(gB + k0 +     rk32, lB + 4096);
    GLDS16(gB + k0 + 2 * rk32, lB + 8192);
    GLDS16(gB + k0 + 3 * rk32, lB + 12288);
    __syncthreads();

#pragma unroll
    for (int h = 0; h < 2; h++) {
      const int hx = h << 6;                    // toggles physical-chunk bit 2
      i32x4 af[4], bfr[4];
#pragma unroll
      for (int i = 0; i < 4; i++)
        af[i] = *(const i32x4*)(As + ((abase + (i << 11)) ^ hx));
#pragma unroll
      for (int j = 0; j < 4; j++)
        bfr[j] = *(const i32x4*)(Bs + ((bbase + (j << 11)) ^ hx));

#pragma unroll
      for (int i = 0; i < 4; i++)
#pragma unroll
        for (int j = 0; j < 4; j++)
          acc[i][j] = __builtin_amdgcn_mfma_i32_16x16x64_i8(af[i], bfr[j],
                                                            acc[i][j], 0, 0, 0);
    }
    __syncthreads();
  }

  // epilogue: C/D layout col = lane&15 (n), row = quad*4 + reg (m)
  double lsum = 0.0;

  if (MODE == 0) {
    const float gs = sc0[0] * sc1[0];
#pragma unroll
    for (int i = 0; i < 4; i++) {
      const int mb = m0 + wm + (i << 4) + (qd << 2);
#pragma unroll
      for (int j = 0; j < 4; j++) {
        const int n = n0 + wn + (j << 4) + wr;
#pragma unroll
        for (int r2 = 0; r2 < 4; r2++) {
          float g = (float)acc[i][j][r2] * gs;
          float s = g / (1.0f + expf(-g));          // silu
          __builtin_nontemporal_store(s, &Cout[(size_t)(mb + r2) * N + n]);
          lsum += (double)fabsf(s);
        }
      }
    }
  } else if (MODE == 1) {
    const float up_s  = sc0[0] * sc1[0];
    const float ga_s  = (float)(sums[0] / (double)NN) + 1e-8f;
    const float combo = ga_s * up_s;
#pragma unroll
    for (int i = 0; i < 4; i++) {
      const int mb = m0 + wm + (i << 4) + (qd << 2);
#pragma unroll
      for (int j = 0; j < 4; j++) {
        const int n = n0 + wn + (j << 4) + wr;
#pragma unroll
        for (int r2 = 0; r2 < 4; r2++) {
          float up = (float)acc[i][j][r2];
          float ga = __builtin_nontemporal_load(
                         &ga_in[(size_t)(mb + r2) * N + n]);
          float gq = fmaxf(-128.0f, fminf(127.0f, rintf(ga / ga_s)));
          float itv = gq * up * combo;              // same assoc as reference
          __builtin_nontemporal_store(itv, &Cout[(size_t)(mb + r2) * N + n]);
          lsum += (double)fabsf(itv);
        }
      }
    }
  } else {
#pragma unroll
    for (int i = 0; i < 4; i++) {
      const int mb = m0 + wm + (i << 4) + (qd << 2);
#pragma unroll
      for (int j = 0; j < 4; j++) {
        const int n = n0 + wn + (j << 4) + wr;
#pragma unroll
        for (int r2 = 0; r2 < 4; r2++)
          __builtin_nontemporal_store((float)acc[i][j][r2],
                                      &Cout[(size_t)(mb + r2) * N + n]);
      }
    }
  }

  if (MODE != 2) {
    for (int off = 32; off; off >>= 1) lsum += __shfl_down(lsum, off, 64);
    if (lane == 0) red[w] = lsum;
    __syncthreads();
    if (tid == 0) atomicAdd(&sums[MODE], red[0] + red[1] + red[2] + red[3]);
  }
}

// ------------------------------------------------------------- quantize -----
__global__ void quant_inter(const float* __restrict__ inter,
                            char* __restrict__ outq,
                            const double* __restrict__ sums, long long NN,
                            const float* __restrict__ wsd,
                            float* __restrict__ scalar_out, int n4)
{
  const float is = (float)(sums[1] / (double)NN) + 1e-8f;
  if (blockIdx.x == 0 && threadIdx.x == 0) scalar_out[0] = is * wsd[0];
  int stride = gridDim.x * blockDim.x;
  for (int i = blockIdx.x * blockDim.x + threadIdx.x; i < n4; i += stride) {
    f32x4v v = __builtin_nontemporal_load(&((const f32x4v*)inter)[i]);
    i8x4v o;
    o.x = (char)(int)fmaxf(-128.0f, fminf(127.0f, rintf(v.x / is)));
    o.y = (char)(int)fmaxf(-128.0f, fminf(127.0f, rintf(v.y / is)));
    o.z = (char)(int)fmaxf(-128.0f, fminf(127.0f, rintf(v.z / is)));
    o.w = (char)(int)fmaxf(-128.0f, fminf(127.0f, rintf(v.w / is)));
    ((i8x4v*)outq)[i] = o;                 // cacheable: GEMM2 reads it next
  }
}

// ---------------------------------------------------------------- launch ----
extern "C" void kernel_launch(void* const* d_in, const int* in_sizes, int n_in,
                              void* d_out, int out_size, void* d_ws, size_t ws_size,
                              hipStream_t stream) {
  const float* x        = (const float*)d_in[0];
  const float* x_scale  = (const float*)d_in[1];
  const float* qw_gate  = (const float*)d_in[2];
  const float* ws_gate  = (const float*)d_in[3];
  const float* qw_up    = (const float*)d_in[4];
  const float* ws_up    = (const float*)d_in[5];
  const float* qw_down  = (const float*)d_in[6];
  const float* ws_down  = (const float*)d_in[7];
  float* out = (float*)d_out;

  char* ws = (char*)d_ws;
  double* sums = (double*)ws;                 // [0]=sum|ga| [1]=sum|inter|
  size_t off = 256;
  char* xq     = ws + off; off += (size_t)TOK * HD;
  char* wgq    = ws + off; off += (size_t)ID * HD;
  char* wuq    = ws + off; off += (size_t)ID * HD;
  char* wdq    = ws + off; off += (size_t)HD * ID;
  char* interq = ws + off; off += (size_t)TOK * ID;
  float* ga    = (float*)(ws + off); off += (size_t)TOK * ID * 4;
  float* inter = (float*)(ws + off); off += (size_t)TOK * ID * 4;

  const long long NN = (long long)TOK * ID;

  (void)hipMemsetAsync(sums, 0, 16, stream);

  // all four converts in one launch
  conv_all<<<8192, 256, 0, stream>>>(x, xq, qw_gate, wgq, qw_up, wuq,
                                     qw_down, wdq);

  // gate GEMM + silu + sum|ga|
  gemm_i8<0><<<dim3(ID / 128, TOK / 128), 256, 0, stream>>>(
      xq, wgq, TOK, ID, HD, ga, nullptr, x_scale, ws_gate, sums, NN);

  // up GEMM + inter computation + sum|inter|
  gemm_i8<1><<<dim3(ID / 128, TOK / 128), 256, 0, stream>>>(
      xq, wuq, TOK, ID, HD, inter, ga, x_scale, ws_up, sums, NN);

  // quantize inter -> int8; also write scalar output
  quant_inter<<<8192, 256, 0, stream>>>(inter, interq, sums, NN, ws_down,
                                        out + (size_t)TOK * HD, (int)(NN / 4));

  // down GEMM -> final output (exact integers in f32)
  gemm_i8<2><<<dim3(HD / 128, TOK / 128), 256, 0, stream>>>(
      interq, wdq, TOK, HD, ID, out, nullptr, nullptr, nullptr, sums, NN);
}